// Round 1
// baseline (1763.839 us; speedup 1.0000x reference)
//
#include <hip/hip_runtime.h>

#define FCn 64      // FC
#define NCOL 256    // padded logical t-columns (224 used)
#define TEB 64      // edges per block
#define LDP 68      // padded LDS row stride (floats), 272B = 17*16B (keeps b128 alignment)

// ---------------- precompute: fold s, rad_w2/rad_b2, proj_w*, 0.25 into M (64x224), cvec(224), b0s(128)
__global__ __launch_bounds__(256) void precomp_kernel(
    const float* __restrict__ exp_w, const float* __restrict__ exp_b,
    const float* __restrict__ rad_w2, const float* __restrict__ rad_b2,
    const float* __restrict__ proj_w0, const float* __restrict__ proj_b0,
    const float* __restrict__ proj_w1, const float* __restrict__ proj_w2,
    float* __restrict__ Mg, float* __restrict__ cvec, float* __restrict__ b0s)
{
    const int r = blockIdx.x;   // 0..63 -> M row r; 64 -> cvec/b0s
    const int c = threadIdx.x;  // 0..255
    const float* wrow = (r < FCn) ? (rad_w2 + (long long)r * 384) : rad_b2;
    float acc = 0.f;
    if (c < 128) {
        for (int q = 0; q < 128; ++q)
            acc += wrow[q] * (exp_w[q] + exp_b[q]) * proj_w0[q * 128 + c];
    } else if (c < 192) {
        const int d = c - 128;
        for (int q = 0; q < 128; ++q)
            acc += wrow[128 + q] * (exp_w[q] + exp_b[q]) * proj_w1[q * 64 + d];
    } else if (c < 224) {
        const int d = c - 192;
        for (int q = 0; q < 128; ++q)
            acc += wrow[256 + q] * (exp_w[q] + exp_b[q]) * proj_w2[q * 32 + d];
    }
    acc *= 0.25f;  // 1/sqrt(AVG_AGG)
    if (r < FCn) {
        Mg[r * NCOL + c] = acc;
    } else {
        cvec[c] = acc;
        if (c < 128) b0s[c] = 0.25f * proj_b0[c];
    }
}

// ---------------- main fused kernel: 64 edges / block
__global__ __launch_bounds__(256, 3) void edge_kernel(
    const float* __restrict__ edge_attr,    // E x 9
    const float* __restrict__ edge_scalars, // E x 64
    const int*   __restrict__ edge_dst,     // E
    const float* __restrict__ rad_w1,       // 64 x 64
    const float* __restrict__ rad_b1,       // 64
    const float* __restrict__ rad_gamma,    // 64
    const float* __restrict__ rad_beta,     // 64
    const float* __restrict__ Mg,           // 64 x 256 (ws)
    const float* __restrict__ cvec,         // 256 (ws)
    const float* __restrict__ b0s,          // 128 (ws)
    float* __restrict__ out,                // N x 480
    int E)
{
    __shared__ float XT[FCn * LDP];   // [k][e]; reused as Hs^T after LN
    __shared__ float Hb[TEB * LDP];   // [e][c]
    const int t = threadIdx.x;
    const long long e0 = (long long)blockIdx.x * TEB;

    // ---- stage X^T (coalesced float4 global reads, transposed LDS writes)
    #pragma unroll
    for (int i = 0; i < 4; ++i) {
        const int idx = i * 256 + t;   // 0..1023
        const int e  = idx >> 4;       // 0..63
        const int kq = idx & 15;       // float4 chunk along k
        float4 v = make_float4(0.f, 0.f, 0.f, 0.f);
        const long long ge = e0 + e;
        if (ge < (long long)E) v = *(const float4*)(edge_scalars + ge * FCn + kq * 4);
        XT[(kq * 4 + 0) * LDP + e] = v.x;
        XT[(kq * 4 + 1) * LDP + e] = v.y;
        XT[(kq * 4 + 2) * LDP + e] = v.z;
        XT[(kq * 4 + 3) * LDP + e] = v.w;
    }
    __syncthreads();

    // ---- GEMM1: H = X @ W1 + b1  (64e x 64c), per-thread 4x4 tile
    {
        const int eg = t >> 4, cg = t & 15;
        float a[4][4];
        #pragma unroll
        for (int i = 0; i < 4; ++i)
            #pragma unroll
            for (int j = 0; j < 4; ++j) a[i][j] = 0.f;
        for (int k = 0; k < FCn; ++k) {
            const float4 xv = *(const float4*)&XT[k * LDP + eg * 4];
            const float4 wv = *(const float4*)&rad_w1[k * FCn + cg * 4];  // L1-resident
            const float xe[4] = {xv.x, xv.y, xv.z, xv.w};
            const float wc[4] = {wv.x, wv.y, wv.z, wv.w};
            #pragma unroll
            for (int i = 0; i < 4; ++i)
                #pragma unroll
                for (int j = 0; j < 4; ++j)
                    a[i][j] += xe[i] * wc[j];
        }
        const float4 bv = *(const float4*)&rad_b1[cg * 4];
        const float bb[4] = {bv.x, bv.y, bv.z, bv.w};
        #pragma unroll
        for (int i = 0; i < 4; ++i) {
            float4 o;
            o.x = a[i][0] + bb[0]; o.y = a[i][1] + bb[1];
            o.z = a[i][2] + bb[2]; o.w = a[i][3] + bb[3];
            *(float4*)&Hb[(eg * 4 + i) * LDP + cg * 4] = o;
        }
    }
    __syncthreads();

    // ---- LayerNorm + silu per edge-row, write transposed into XT (Hs^T[k][e])
    if (t < TEB) {
        const float4* hrow = (const float4*)&Hb[t * LDP];
        float4 r[16];
        float s1 = 0.f, s2 = 0.f;
        #pragma unroll
        for (int i = 0; i < 16; ++i) {
            r[i] = hrow[i];
            s1 += r[i].x + r[i].y + r[i].z + r[i].w;
            s2 += r[i].x * r[i].x + r[i].y * r[i].y + r[i].z * r[i].z + r[i].w * r[i].w;
        }
        const float mu  = s1 * (1.f / 64.f);
        const float var = s2 * (1.f / 64.f) - mu * mu;
        const float rs  = rsqrtf(var + 1e-5f);
        #pragma unroll
        for (int i = 0; i < 16; ++i) {
            const float4 g = *(const float4*)&rad_gamma[i * 4];
            const float4 b = *(const float4*)&rad_beta[i * 4];
            const float hv[4] = {r[i].x, r[i].y, r[i].z, r[i].w};
            const float gv[4] = {g.x, g.y, g.z, g.w};
            const float bv2[4] = {b.x, b.y, b.z, b.w};
            #pragma unroll
            for (int j = 0; j < 4; ++j) {
                const float x = (hv[j] - mu) * rs * gv[j] + bv2[j];
                const float sw = x / (1.f + __expf(-x));   // silu
                XT[(i * 4 + j) * LDP + t] = sw;
            }
        }
    }
    __syncthreads();

    // ---- GEMM2: T = Hs @ M + cvec  (64e x 224c), per-thread 8 edges x 7 strided cols
    //      logical col c = cg + 32*j, j=0..6  (j 0-3 -> y0 block, 4-5 -> y1, 6 -> y2)
    const int eg = t >> 5;   // 0..7
    const int cg = t & 31;   // 0..31
    float acc[8][7];
    #pragma unroll
    for (int j = 0; j < 7; ++j) {
        const float cv = cvec[cg + 32 * j];
        #pragma unroll
        for (int i = 0; i < 8; ++i) acc[i][j] = cv;
    }
    for (int k = 0; k < FCn; ++k) {
        const float4 h0 = *(const float4*)&XT[k * LDP + eg * 8];
        const float4 h1 = *(const float4*)&XT[k * LDP + eg * 8 + 4];
        const float he[8] = {h0.x, h0.y, h0.z, h0.w, h1.x, h1.y, h1.z, h1.w};
        float m[7];
        #pragma unroll
        for (int j = 0; j < 7; ++j) m[j] = Mg[k * NCOL + cg + 32 * j];  // L2-resident, coalesced
        #pragma unroll
        for (int i = 0; i < 8; ++i)
            #pragma unroll
            for (int j = 0; j < 7; ++j)
                acc[i][j] += he[i] * m[j];
    }

    // ---- epilogue: per-edge y assembly + atomic scatter (15 atomics / thread / edge)
    float b0v[4];
    #pragma unroll
    for (int j = 0; j < 4; ++j) b0v[j] = b0s[cg + 32 * j];
    #pragma unroll
    for (int i = 0; i < 8; ++i) {
        const long long ge = e0 + eg * 8 + i;
        if (ge >= (long long)E) break;
        const int dst = edge_dst[ge];
        float* ob = out + (long long)dst * 480;
        const float* ea = edge_attr + ge * 9;
        const float sh0 = ea[0];
        #pragma unroll
        for (int j = 0; j < 4; ++j) {
            const int c = cg + 32 * j;                    // c < 128
            atomicAdd(ob + c, sh0 * acc[i][j] + b0v[j]);
        }
        const float s10 = ea[1], s11 = ea[2], s12 = ea[3];
        #pragma unroll
        for (int j = 4; j < 6; ++j) {
            const int d = cg + 32 * (j - 4);              // d < 64
            const float tv = acc[i][j];
            atomicAdd(ob + 128 + d * 3 + 0, tv * s10);
            atomicAdd(ob + 128 + d * 3 + 1, tv * s11);
            atomicAdd(ob + 128 + d * 3 + 2, tv * s12);
        }
        {
            const float tv = acc[i][6];                   // d = cg < 32
            atomicAdd(ob + 320 + cg * 5 + 0, tv * ea[4]);
            atomicAdd(ob + 320 + cg * 5 + 1, tv * ea[5]);
            atomicAdd(ob + 320 + cg * 5 + 2, tv * ea[6]);
            atomicAdd(ob + 320 + cg * 5 + 3, tv * ea[7]);
            atomicAdd(ob + 320 + cg * 5 + 4, tv * ea[8]);
        }
    }
}

extern "C" void kernel_launch(void* const* d_in, const int* in_sizes, int n_in,
                              void* d_out, int out_size, void* d_ws, size_t ws_size,
                              hipStream_t stream)
{
    // setup_inputs order:
    // 0 node_input (unused), 1 edge_attr, 2 edge_scalars, 3 edge_src (unused),
    // 4 edge_dst, 5 batch (unused), 6 exp_w, 7 exp_b, 8 rad_w1, 9 rad_b1,
    // 10 rad_gamma, 11 rad_beta, 12 rad_w2, 13 rad_b2, 14 proj_w0, 15 proj_b0,
    // 16 proj_w1, 17 proj_w2
    const float* edge_attr    = (const float*)d_in[1];
    const float* edge_scalars = (const float*)d_in[2];
    const int*   edge_dst     = (const int*)d_in[4];
    const float* exp_w     = (const float*)d_in[6];
    const float* exp_b     = (const float*)d_in[7];
    const float* rad_w1    = (const float*)d_in[8];
    const float* rad_b1    = (const float*)d_in[9];
    const float* rad_gamma = (const float*)d_in[10];
    const float* rad_beta  = (const float*)d_in[11];
    const float* rad_w2    = (const float*)d_in[12];
    const float* rad_b2    = (const float*)d_in[13];
    const float* proj_w0   = (const float*)d_in[14];
    const float* proj_b0   = (const float*)d_in[15];
    const float* proj_w1   = (const float*)d_in[16];
    const float* proj_w2   = (const float*)d_in[17];
    float* out = (float*)d_out;
    const int E = in_sizes[4];

    float* Mg   = (float*)d_ws;           // 64*256 floats
    float* cvec = Mg + FCn * NCOL;        // 256 floats
    float* b0s  = cvec + NCOL;            // 128 floats

    hipMemsetAsync(d_out, 0, (size_t)out_size * sizeof(float), stream);
    precomp_kernel<<<FCn + 1, 256, 0, stream>>>(exp_w, exp_b, rad_w2, rad_b2,
                                                proj_w0, proj_b0, proj_w1, proj_w2,
                                                Mg, cvec, b0s);
    const int blocks = (E + TEB - 1) / TEB;
    edge_kernel<<<blocks, 256, 0, stream>>>(edge_attr, edge_scalars, edge_dst,
                                            rad_w1, rad_b1, rad_gamma, rad_beta,
                                            Mg, cvec, b0s, out, E);
}

// Round 2
// 617.532 us; speedup vs baseline: 2.8563x; 2.8563x over previous
//
#include <hip/hip_runtime.h>

#define FCn 64      // FC
#define NCOL 256    // padded logical t-columns (224 used)
#define TCOL 224    // stored t-columns per edge
#define TEB 64      // edges per block
#define LDP 68      // padded LDS row stride (floats)

// ---------------- precompute: fold s, rad_w2/rad_b2, proj_w*, 0.25 into M (64x224), cvec(224), b0s(128)
__global__ __launch_bounds__(256) void precomp_kernel(
    const float* __restrict__ exp_w, const float* __restrict__ exp_b,
    const float* __restrict__ rad_w2, const float* __restrict__ rad_b2,
    const float* __restrict__ proj_w0, const float* __restrict__ proj_b0,
    const float* __restrict__ proj_w1, const float* __restrict__ proj_w2,
    float* __restrict__ Mg, float* __restrict__ cvec, float* __restrict__ b0s)
{
    const int r = blockIdx.x;   // 0..63 -> M row r; 64 -> cvec/b0s
    const int c = threadIdx.x;  // 0..255
    const float* wrow = (r < FCn) ? (rad_w2 + (long long)r * 384) : rad_b2;
    float acc = 0.f;
    if (c < 128) {
        for (int q = 0; q < 128; ++q)
            acc += wrow[q] * (exp_w[q] + exp_b[q]) * proj_w0[q * 128 + c];
    } else if (c < 192) {
        const int d = c - 128;
        for (int q = 0; q < 128; ++q)
            acc += wrow[128 + q] * (exp_w[q] + exp_b[q]) * proj_w1[q * 64 + d];
    } else if (c < 224) {
        const int d = c - 192;
        for (int q = 0; q < 128; ++q)
            acc += wrow[256 + q] * (exp_w[q] + exp_b[q]) * proj_w2[q * 32 + d];
    }
    acc *= 0.25f;  // 1/sqrt(AVG_AGG)
    if (r < FCn) {
        Mg[r * NCOL + c] = acc;
    } else {
        cvec[c] = acc;
        if (c < 128) b0s[c] = 0.25f * proj_b0[c];
    }
}

// ---------------- shared GEMM body macro-free helper: computes acc[8][7] of T for 64 edges/block
// Pass 1: compute per-edge T (224 cols) and store to global ws (no atomics).
__global__ __launch_bounds__(256, 3) void compute_T_kernel(
    const float* __restrict__ edge_scalars, // E x 64
    const float* __restrict__ rad_w1,       // 64 x 64
    const float* __restrict__ rad_b1,       // 64
    const float* __restrict__ rad_gamma,    // 64
    const float* __restrict__ rad_beta,     // 64
    const float* __restrict__ Mg,           // 64 x 256 (ws)
    const float* __restrict__ cvec,         // 256 (ws)
    float* __restrict__ T,                  // E x 224 (ws)
    int E)
{
    __shared__ float XT[FCn * LDP];   // [k][e]; reused as Hs^T after LN
    __shared__ float Hb[TEB * LDP];   // [e][c]
    const int t = threadIdx.x;
    const long long e0 = (long long)blockIdx.x * TEB;

    // ---- stage X^T
    #pragma unroll
    for (int i = 0; i < 4; ++i) {
        const int idx = i * 256 + t;
        const int e  = idx >> 4;
        const int kq = idx & 15;
        float4 v = make_float4(0.f, 0.f, 0.f, 0.f);
        const long long ge = e0 + e;
        if (ge < (long long)E) v = *(const float4*)(edge_scalars + ge * FCn + kq * 4);
        XT[(kq * 4 + 0) * LDP + e] = v.x;
        XT[(kq * 4 + 1) * LDP + e] = v.y;
        XT[(kq * 4 + 2) * LDP + e] = v.z;
        XT[(kq * 4 + 3) * LDP + e] = v.w;
    }
    __syncthreads();

    // ---- GEMM1: H = X @ W1 + b1
    {
        const int eg = t >> 4, cg = t & 15;
        float a[4][4];
        #pragma unroll
        for (int i = 0; i < 4; ++i)
            #pragma unroll
            for (int j = 0; j < 4; ++j) a[i][j] = 0.f;
        for (int k = 0; k < FCn; ++k) {
            const float4 xv = *(const float4*)&XT[k * LDP + eg * 4];
            const float4 wv = *(const float4*)&rad_w1[k * FCn + cg * 4];
            const float xe[4] = {xv.x, xv.y, xv.z, xv.w};
            const float wc[4] = {wv.x, wv.y, wv.z, wv.w};
            #pragma unroll
            for (int i = 0; i < 4; ++i)
                #pragma unroll
                for (int j = 0; j < 4; ++j)
                    a[i][j] += xe[i] * wc[j];
        }
        const float4 bv = *(const float4*)&rad_b1[cg * 4];
        const float bb[4] = {bv.x, bv.y, bv.z, bv.w};
        #pragma unroll
        for (int i = 0; i < 4; ++i) {
            float4 o;
            o.x = a[i][0] + bb[0]; o.y = a[i][1] + bb[1];
            o.z = a[i][2] + bb[2]; o.w = a[i][3] + bb[3];
            *(float4*)&Hb[(eg * 4 + i) * LDP + cg * 4] = o;
        }
    }
    __syncthreads();

    // ---- LayerNorm + silu, transpose into XT
    if (t < TEB) {
        const float4* hrow = (const float4*)&Hb[t * LDP];
        float4 r[16];
        float s1 = 0.f, s2 = 0.f;
        #pragma unroll
        for (int i = 0; i < 16; ++i) {
            r[i] = hrow[i];
            s1 += r[i].x + r[i].y + r[i].z + r[i].w;
            s2 += r[i].x * r[i].x + r[i].y * r[i].y + r[i].z * r[i].z + r[i].w * r[i].w;
        }
        const float mu  = s1 * (1.f / 64.f);
        const float var = s2 * (1.f / 64.f) - mu * mu;
        const float rs  = rsqrtf(var + 1e-5f);
        #pragma unroll
        for (int i = 0; i < 16; ++i) {
            const float4 g = *(const float4*)&rad_gamma[i * 4];
            const float4 b = *(const float4*)&rad_beta[i * 4];
            const float hv[4] = {r[i].x, r[i].y, r[i].z, r[i].w};
            const float gv[4] = {g.x, g.y, g.z, g.w};
            const float bv2[4] = {b.x, b.y, b.z, b.w};
            #pragma unroll
            for (int j = 0; j < 4; ++j) {
                const float x = (hv[j] - mu) * rs * gv[j] + bv2[j];
                const float sw = x / (1.f + __expf(-x));
                XT[(i * 4 + j) * LDP + t] = sw;
            }
        }
    }
    __syncthreads();

    // ---- GEMM2: T = Hs @ M + cvec, then store T rows (coalesced, no atomics)
    const int eg = t >> 5;   // 0..7
    const int cg = t & 31;   // 0..31
    float acc[8][7];
    #pragma unroll
    for (int j = 0; j < 7; ++j) {
        const float cv = cvec[cg + 32 * j];
        #pragma unroll
        for (int i = 0; i < 8; ++i) acc[i][j] = cv;
    }
    for (int k = 0; k < FCn; ++k) {
        const float4 h0 = *(const float4*)&XT[k * LDP + eg * 8];
        const float4 h1 = *(const float4*)&XT[k * LDP + eg * 8 + 4];
        const float he[8] = {h0.x, h0.y, h0.z, h0.w, h1.x, h1.y, h1.z, h1.w};
        float m[7];
        #pragma unroll
        for (int j = 0; j < 7; ++j) m[j] = Mg[k * NCOL + cg + 32 * j];
        #pragma unroll
        for (int i = 0; i < 8; ++i)
            #pragma unroll
            for (int j = 0; j < 7; ++j)
                acc[i][j] += he[i] * m[j];
    }
    #pragma unroll
    for (int i = 0; i < 8; ++i) {
        const long long ge = e0 + eg * 8 + i;
        if (ge >= (long long)E) break;
        float* trow = T + ge * TCOL;
        #pragma unroll
        for (int j = 0; j < 7; ++j) trow[cg + 32 * j] = acc[i][j];
    }
}

// ---------------- CSR build
__global__ __launch_bounds__(256) void hist_kernel(const int* __restrict__ dst, int* __restrict__ cnt, int E)
{
    for (int e = blockIdx.x * 256 + threadIdx.x; e < E; e += gridDim.x * 256)
        atomicAdd(&cnt[dst[e]], 1);
}

__global__ __launch_bounds__(256) void scan_kernel(const int* __restrict__ cnt, int* __restrict__ off,
                                                   int* __restrict__ cur, int Nn, int Etot)
{
    __shared__ int part[256];
    __shared__ int spart[257];
    const int t = threadIdx.x;
    const int per = (Nn + 255) / 256;
    int s = 0;
    for (int i = 0; i < per; ++i) {
        const int idx = t * per + i;
        if (idx < Nn) s += cnt[idx];
    }
    part[t] = s;
    __syncthreads();
    if (t == 0) {
        int run = 0;
        spart[0] = 0;
        for (int i = 0; i < 256; ++i) { run += part[i]; spart[i + 1] = run; }
    }
    __syncthreads();
    int run = spart[t];
    for (int i = 0; i < per; ++i) {
        const int idx = t * per + i;
        if (idx < Nn) { off[idx] = run; cur[idx] = run; run += cnt[idx]; }
    }
    if (t == 0) off[Nn] = Etot;
}

__global__ __launch_bounds__(256) void scatter_kernel(const int* __restrict__ dst, int* __restrict__ cur,
                                                      int* __restrict__ eids, int E)
{
    for (int e = blockIdx.x * 256 + threadIdx.x; e < E; e += gridDim.x * 256) {
        const int pos = atomicAdd(&cur[dst[e]], 1);
        eids[pos] = e;
    }
}

// ---------------- gather: one block per node, 480 output-owning threads, zero float atomics
__global__ __launch_bounds__(512) void gather_kernel(
    const float* __restrict__ T,          // E x 224
    const float* __restrict__ edge_attr,  // E x 9
    const int*   __restrict__ off,        // N+1
    const int*   __restrict__ eids,       // E
    const float* __restrict__ b0s,        // 128
    float* __restrict__ out)              // N x 480
{
    __shared__ float Trow[4][TCOL];
    __shared__ float Ea[4][12];
    const int n = blockIdx.x;
    const int t = threadIdx.x;
    const int beg = off[n], end = off[n + 1];

    // per-thread output mapping: out col t -> (T col, edge_attr col)
    int tIdx = 0, eaIdx = 0;
    if (t < 128)      { tIdx = t;                    eaIdx = 0; }
    else if (t < 320) { const int idx = t - 128; tIdx = 128 + idx / 3; eaIdx = 1 + idx % 3; }
    else if (t < 480) { const int idx = t - 320; tIdx = 192 + idx / 5; eaIdx = 4 + idx % 5; }

    float acc = 0.f;
    for (int base = beg; base < end; base += 4) {
        const int m = min(4, end - base);
        // stage up to 4 T rows (224 float4-loads) + edge_attr rows
        if (t < 224) {
            const int row = t / 56, q = t % 56;
            if (row < m) {
                const int eid = eids[base + row];
                *(float4*)&Trow[row][q * 4] = *(const float4*)(T + (long long)eid * TCOL + q * 4);
            }
        } else if (t >= 256 && t < 256 + 36) {
            const int row = (t - 256) / 9, j = (t - 256) % 9;
            if (row < m) {
                const int eid = eids[base + row];
                Ea[row][j] = edge_attr[(long long)eid * 9 + j];
            }
        }
        __syncthreads();
        #pragma unroll
        for (int i = 0; i < 4; ++i)
            if (i < m) acc += Trow[i][tIdx] * Ea[i][eaIdx];
        __syncthreads();
    }

    if (t < 480) {
        float r = acc;
        if (t < 128) r += (float)(end - beg) * b0s[t];
        out[(long long)n * 480 + t] = r;
    }
}

// ---------------- fallback (R1): fused atomic-scatter kernel, used only if ws too small
__global__ __launch_bounds__(256, 3) void edge_kernel_atomic(
    const float* __restrict__ edge_attr, const float* __restrict__ edge_scalars,
    const int* __restrict__ edge_dst, const float* __restrict__ rad_w1,
    const float* __restrict__ rad_b1, const float* __restrict__ rad_gamma,
    const float* __restrict__ rad_beta, const float* __restrict__ Mg,
    const float* __restrict__ cvec, const float* __restrict__ b0s,
    float* __restrict__ out, int E)
{
    __shared__ float XT[FCn * LDP];
    __shared__ float Hb[TEB * LDP];
    const int t = threadIdx.x;
    const long long e0 = (long long)blockIdx.x * TEB;
    #pragma unroll
    for (int i = 0; i < 4; ++i) {
        const int idx = i * 256 + t;
        const int e = idx >> 4, kq = idx & 15;
        float4 v = make_float4(0.f, 0.f, 0.f, 0.f);
        const long long ge = e0 + e;
        if (ge < (long long)E) v = *(const float4*)(edge_scalars + ge * FCn + kq * 4);
        XT[(kq * 4 + 0) * LDP + e] = v.x;
        XT[(kq * 4 + 1) * LDP + e] = v.y;
        XT[(kq * 4 + 2) * LDP + e] = v.z;
        XT[(kq * 4 + 3) * LDP + e] = v.w;
    }
    __syncthreads();
    {
        const int eg = t >> 4, cg = t & 15;
        float a[4][4];
        #pragma unroll
        for (int i = 0; i < 4; ++i)
            #pragma unroll
            for (int j = 0; j < 4; ++j) a[i][j] = 0.f;
        for (int k = 0; k < FCn; ++k) {
            const float4 xv = *(const float4*)&XT[k * LDP + eg * 4];
            const float4 wv = *(const float4*)&rad_w1[k * FCn + cg * 4];
            const float xe[4] = {xv.x, xv.y, xv.z, xv.w};
            const float wc[4] = {wv.x, wv.y, wv.z, wv.w};
            #pragma unroll
            for (int i = 0; i < 4; ++i)
                #pragma unroll
                for (int j = 0; j < 4; ++j) a[i][j] += xe[i] * wc[j];
        }
        const float4 bv = *(const float4*)&rad_b1[cg * 4];
        const float bb[4] = {bv.x, bv.y, bv.z, bv.w};
        #pragma unroll
        for (int i = 0; i < 4; ++i) {
            float4 o;
            o.x = a[i][0] + bb[0]; o.y = a[i][1] + bb[1];
            o.z = a[i][2] + bb[2]; o.w = a[i][3] + bb[3];
            *(float4*)&Hb[(eg * 4 + i) * LDP + cg * 4] = o;
        }
    }
    __syncthreads();
    if (t < TEB) {
        const float4* hrow = (const float4*)&Hb[t * LDP];
        float4 r[16];
        float s1 = 0.f, s2 = 0.f;
        #pragma unroll
        for (int i = 0; i < 16; ++i) {
            r[i] = hrow[i];
            s1 += r[i].x + r[i].y + r[i].z + r[i].w;
            s2 += r[i].x * r[i].x + r[i].y * r[i].y + r[i].z * r[i].z + r[i].w * r[i].w;
        }
        const float mu = s1 * (1.f / 64.f);
        const float var = s2 * (1.f / 64.f) - mu * mu;
        const float rs = rsqrtf(var + 1e-5f);
        #pragma unroll
        for (int i = 0; i < 16; ++i) {
            const float4 g = *(const float4*)&rad_gamma[i * 4];
            const float4 b = *(const float4*)&rad_beta[i * 4];
            const float hv[4] = {r[i].x, r[i].y, r[i].z, r[i].w};
            const float gv[4] = {g.x, g.y, g.z, g.w};
            const float bv2[4] = {b.x, b.y, b.z, b.w};
            #pragma unroll
            for (int j = 0; j < 4; ++j) {
                const float x = (hv[j] - mu) * rs * gv[j] + bv2[j];
                XT[(i * 4 + j) * LDP + t] = x / (1.f + __expf(-x));
            }
        }
    }
    __syncthreads();
    const int eg = t >> 5, cg = t & 31;
    float acc[8][7];
    #pragma unroll
    for (int j = 0; j < 7; ++j) {
        const float cv = cvec[cg + 32 * j];
        #pragma unroll
        for (int i = 0; i < 8; ++i) acc[i][j] = cv;
    }
    for (int k = 0; k < FCn; ++k) {
        const float4 h0 = *(const float4*)&XT[k * LDP + eg * 8];
        const float4 h1 = *(const float4*)&XT[k * LDP + eg * 8 + 4];
        const float he[8] = {h0.x, h0.y, h0.z, h0.w, h1.x, h1.y, h1.z, h1.w};
        float m[7];
        #pragma unroll
        for (int j = 0; j < 7; ++j) m[j] = Mg[k * NCOL + cg + 32 * j];
        #pragma unroll
        for (int i = 0; i < 8; ++i)
            #pragma unroll
            for (int j = 0; j < 7; ++j) acc[i][j] += he[i] * m[j];
    }
    float b0v[4];
    #pragma unroll
    for (int j = 0; j < 4; ++j) b0v[j] = b0s[cg + 32 * j];
    #pragma unroll
    for (int i = 0; i < 8; ++i) {
        const long long ge = e0 + eg * 8 + i;
        if (ge >= (long long)E) break;
        const int dst = edge_dst[ge];
        float* ob = out + (long long)dst * 480;
        const float* ea = edge_attr + ge * 9;
        const float sh0 = ea[0];
        #pragma unroll
        for (int j = 0; j < 4; ++j) atomicAdd(ob + cg + 32 * j, sh0 * acc[i][j] + b0v[j]);
        const float s10 = ea[1], s11 = ea[2], s12 = ea[3];
        #pragma unroll
        for (int j = 4; j < 6; ++j) {
            const int d = cg + 32 * (j - 4);
            const float tv = acc[i][j];
            atomicAdd(ob + 128 + d * 3 + 0, tv * s10);
            atomicAdd(ob + 128 + d * 3 + 1, tv * s11);
            atomicAdd(ob + 128 + d * 3 + 2, tv * s12);
        }
        {
            const float tv = acc[i][6];
            atomicAdd(ob + 320 + cg * 5 + 0, tv * edge_attr[ge * 9 + 4]);
            atomicAdd(ob + 320 + cg * 5 + 1, tv * edge_attr[ge * 9 + 5]);
            atomicAdd(ob + 320 + cg * 5 + 2, tv * edge_attr[ge * 9 + 6]);
            atomicAdd(ob + 320 + cg * 5 + 3, tv * edge_attr[ge * 9 + 7]);
            atomicAdd(ob + 320 + cg * 5 + 4, tv * edge_attr[ge * 9 + 8]);
        }
    }
}

extern "C" void kernel_launch(void* const* d_in, const int* in_sizes, int n_in,
                              void* d_out, int out_size, void* d_ws, size_t ws_size,
                              hipStream_t stream)
{
    const float* edge_attr    = (const float*)d_in[1];
    const float* edge_scalars = (const float*)d_in[2];
    const int*   edge_dst     = (const int*)d_in[4];
    const float* exp_w     = (const float*)d_in[6];
    const float* exp_b     = (const float*)d_in[7];
    const float* rad_w1    = (const float*)d_in[8];
    const float* rad_b1    = (const float*)d_in[9];
    const float* rad_gamma = (const float*)d_in[10];
    const float* rad_beta  = (const float*)d_in[11];
    const float* rad_w2    = (const float*)d_in[12];
    const float* rad_b2    = (const float*)d_in[13];
    const float* proj_w0   = (const float*)d_in[14];
    const float* proj_b0   = (const float*)d_in[15];
    const float* proj_w1   = (const float*)d_in[16];
    const float* proj_w2   = (const float*)d_in[17];
    float* out = (float*)d_out;
    const int E = in_sizes[4];
    const int Nn = out_size / 480;

    // ws layout
    float* Mg   = (float*)d_ws;                 // 64*256
    float* cvec = Mg + FCn * NCOL;              // 256
    float* b0s  = cvec + NCOL;                  // 128
    int* off  = (int*)(b0s + 128);              // Nn+1
    int* cnt  = off + (Nn + 1);                 // Nn
    int* cur  = cnt + Nn;                       // Nn
    int* eids = cur + Nn;                       // E
    size_t tOff = (size_t)((char*)(eids + E) - (char*)d_ws);
    tOff = (tOff + 15) & ~(size_t)15;
    float* T = (float*)((char*)d_ws + tOff);    // E x 224
    const size_t need = tOff + (size_t)E * TCOL * sizeof(float);

    precomp_kernel<<<FCn + 1, 256, 0, stream>>>(exp_w, exp_b, rad_w2, rad_b2,
                                                proj_w0, proj_b0, proj_w1, proj_w2,
                                                Mg, cvec, b0s);

    if (need <= ws_size) {
        // fast path: materialize T, build CSR, gather (no float atomics)
        hipMemsetAsync(cnt, 0, (size_t)Nn * sizeof(int), stream);
        const int blocks = (E + TEB - 1) / TEB;
        compute_T_kernel<<<blocks, 256, 0, stream>>>(edge_scalars, rad_w1, rad_b1,
                                                     rad_gamma, rad_beta, Mg, cvec, T, E);
        hist_kernel<<<512, 256, 0, stream>>>(edge_dst, cnt, E);
        scan_kernel<<<1, 256, 0, stream>>>(cnt, off, cur, Nn, E);
        scatter_kernel<<<512, 256, 0, stream>>>(edge_dst, cur, eids, E);
        gather_kernel<<<Nn, 512, 0, stream>>>(T, edge_attr, off, eids, b0s, out);
    } else {
        // fallback: atomic scatter path
        hipMemsetAsync(d_out, 0, (size_t)out_size * sizeof(float), stream);
        const int blocks = (E + TEB - 1) / TEB;
        edge_kernel_atomic<<<blocks, 256, 0, stream>>>(edge_attr, edge_scalars, edge_dst,
                                                       rad_w1, rad_b1, rad_gamma, rad_beta,
                                                       Mg, cvec, b0s, out, E);
    }
}